// Round 1
// baseline (57.735 us; speedup 1.0000x reference)
//
#include <hip/hip_runtime.h>
#include <math.h>

#define B_SZ 2
#define T_SZ 512
#define D_SZ 64
#define ELEMS 4096   // D*D

// Kernel 1: per-(b,t) LayerNorm over D*D + affine, row-dot with dt_w,
// softplus, decay = exp(softplus(dot+dt_b) * -exp(log_A[r])).
// xn -> xn_out (which is d_out), decay -> decay_out (d_ws).
__global__ __launch_bounds__(256) void ln_dt_kernel(
    const float* __restrict__ x, const float* __restrict__ log_A,
    const float* __restrict__ dt_w, const float* __restrict__ dt_b,
    const float* __restrict__ ln_w, const float* __restrict__ ln_b,
    float* __restrict__ xn_out, float* __restrict__ decay_out)
{
    const int bt  = blockIdx.x;            // 0..B*T-1
    const int tid = threadIdx.x;           // 0..255
    const size_t base = (size_t)bt * ELEMS;

    // Each thread loads 4 float4s (16 elems): float4 indices tid + 256k.
    float4 v[4];
    float sum = 0.f, sumsq = 0.f;
    const float4* xv4 = reinterpret_cast<const float4*>(x + base);
#pragma unroll
    for (int k = 0; k < 4; ++k) {
        v[k] = xv4[tid + 256 * k];
        sum   += v[k].x + v[k].y + v[k].z + v[k].w;
        sumsq += v[k].x * v[k].x + v[k].y * v[k].y + v[k].z * v[k].z + v[k].w * v[k].w;
    }

    // Block reduction (4 waves of 64)
    __shared__ float red0[4], red1[4];
#pragma unroll
    for (int off = 32; off; off >>= 1) {
        sum   += __shfl_down(sum, off);
        sumsq += __shfl_down(sumsq, off);
    }
    const int wave = tid >> 6;
    if ((tid & 63) == 0) { red0[wave] = sum; red1[wave] = sumsq; }
    __syncthreads();
    sum   = red0[0] + red0[1] + red0[2] + red0[3];
    sumsq = red1[0] + red1[1] + red1[2] + red1[3];

    const float mu = sum * (1.f / ELEMS);
    const float var = sumsq * (1.f / ELEMS) - mu * mu;
    const float rs = rsqrtf(var + 1e-5f);

    // Normalize + affine, write xn, accumulate row-dot partials.
    // float4 index f covers row f>>4, cols 4*(f&15)..+3.
    const float4* w4p = reinterpret_cast<const float4*>(ln_w);
    const float4* b4p = reinterpret_cast<const float4*>(ln_b);
    const float4* dw4 = reinterpret_cast<const float4*>(dt_w);
    float4* xo4 = reinterpret_cast<float4*>(xn_out + base);
    float dot[4] = {0.f, 0.f, 0.f, 0.f};
#pragma unroll
    for (int k = 0; k < 4; ++k) {
        const int f = tid + 256 * k;
        float4 w4 = w4p[f];
        float4 b4 = b4p[f];
        float4 xn;
        xn.x = (v[k].x - mu) * rs * w4.x + b4.x;
        xn.y = (v[k].y - mu) * rs * w4.y + b4.y;
        xn.z = (v[k].z - mu) * rs * w4.z + b4.z;
        xn.w = (v[k].w - mu) * rs * w4.w + b4.w;
        xo4[f] = xn;
        float4 wv = dw4[f & 15];
        dot[k] += xn.x * wv.x + xn.y * wv.y + xn.z * wv.z + xn.w * wv.w;
    }

    // Reduce each dot[k] across the 16 lanes sharing tid>>4 (aligned groups).
#pragma unroll
    for (int m = 1; m <= 8; m <<= 1) {
#pragma unroll
        for (int k = 0; k < 4; ++k) dot[k] += __shfl_xor(dot[k], m);
    }

    if ((tid & 15) == 0) {
        const int m = tid >> 4;              // 0..15
        const float db = dt_b[0];
#pragma unroll
        for (int k = 0; k < 4; ++k) {
            const int r = m + 16 * k;        // row index 0..63
            const float z = dot[k] + db;
            // stable softplus
            const float dt = (z > 20.f) ? z : log1pf(expf(z));
            const float A = -expf(log_A[r]);
            decay_out[(size_t)bt * D_SZ + r] = expf(dt * A);
        }
    }
}

// Kernel 2: per-(b,r) sequential scan over T. One wave per (b,r); lane = c.
// In-place on xn buffer (reads xn_t, overwrites with S_t at same address).
__global__ __launch_bounds__(256) void scan_kernel(
    const float* __restrict__ decay, float* __restrict__ xn_io)
{
    const int gtid = blockIdx.x * blockDim.x + threadIdx.x;
    const int wid  = gtid >> 6;        // 0..127
    const int lane = threadIdx.x & 63; // c
    const int b = wid >> 6;            // 0..1
    const int r = wid & 63;            // 0..63

    const float* dptr = decay + (size_t)b * (T_SZ * D_SZ) + r;
    float* p = xn_io + (size_t)b * ((size_t)T_SZ * ELEMS) + r * D_SZ + lane;

    float S = 0.f;
    for (int t = 0; t < T_SZ; ++t) {
        const float d  = dptr[(size_t)t * D_SZ];
        const float xv = p[(size_t)t * ELEMS];
        S = fmaf(S, d, xv);
        p[(size_t)t * ELEMS] = S;
    }
}

extern "C" void kernel_launch(void* const* d_in, const int* in_sizes, int n_in,
                              void* d_out, int out_size, void* d_ws, size_t ws_size,
                              hipStream_t stream) {
    const float* x     = (const float*)d_in[0];
    const float* log_A = (const float*)d_in[1];
    const float* dt_w  = (const float*)d_in[2];
    const float* dt_b  = (const float*)d_in[3];
    const float* ln_w  = (const float*)d_in[4];
    const float* ln_b  = (const float*)d_in[5];
    float* out   = (float*)d_out;
    float* decay = (float*)d_ws;   // B*T*D floats = 256 KB

    ln_dt_kernel<<<B_SZ * T_SZ, 256, 0, stream>>>(
        x, log_A, dt_w, dt_b, ln_w, ln_b, out, decay);

    scan_kernel<<<(B_SZ * D_SZ * 64) / 256, 256, 0, stream>>>(decay, out);
}